// Round 1
// 276.253 us; speedup vs baseline: 1.3351x; 1.3351x over previous
//
#include <hip/hip_runtime.h>
#include <math.h>

#define BB 16
#define NN 8192
#define DD 128
#define CC 64
#define ROWS (BB*NN)            // 131072
#define INV_TEMP (1.0f/6.0f)    // temp = 2*(1+192/96) = 6
#define NEGF (-3.402823e38f)
#define LDSS 132                // k_ortho LDS row stride

#define RPB 128                 // rows per block in k_main
#define CHW 32                  // chunk width (floats of j)
#define XST 34                  // LDS row stride in dwords (2-way conflict max, 8B aligned)

__device__ __forceinline__ unsigned f2bf(float f) {
    unsigned u = __builtin_bit_cast(unsigned, f);
    return (u + 0x7fffu + ((u >> 16) & 1u)) >> 16;   // RNE
}
__device__ __forceinline__ float bflo(unsigned u) { return __builtin_bit_cast(float, u << 16); }
__device__ __forceinline__ float bfhi(unsigned u) { return __builtin_bit_cast(float, u & 0xffff0000u); }

// ---------------------------------------------------------------------------
// k_main: 2 threads per row (c-halves). Waves 0-1: c 0..31 for rows 0..127;
// waves 2-3: c 32..63.
// Phase 1: x staged through LDS with a register-prefetch pipeline (loads for
//   chunk ch+1 issued before the score compute on chunk ch).
// Phase 3: barrier-free streaming epilogue — per-row w/si published to LDS
//   once, then each (row, d-slice) is computed in the coalesced layout
//   directly from global x (L3-hot 2nd read) + L1-resident dict gathers.
// Column sums come from the LDS-staged bf16 q (no 64-way LDS atomics).
// ---------------------------------------------------------------------------
__global__ __launch_bounds__(256, 4) void k_main(
    const float* __restrict__ x, const float* __restrict__ dict,
    float* __restrict__ xcg, float* __restrict__ xrg,
    unsigned* __restrict__ qg, float* __restrict__ colpart)
{
    __shared__ __align__(16) float bufA[RPB * XST];   // 17408 B: x stage, t4 exchange, q stage
    __shared__ float red2[RPB][2];
    __shared__ float colsumA[CC];
    __shared__ __align__(16) float w4s[RPB][4];       // top-4 softmax weights per row
    __shared__ __align__(16) int   si4s[RPB][4];      // top-4 indices per row

    const int tid   = threadIdx.x;
    const int rloc  = tid & (RPB - 1);
    const int chalf = tid >> 7;
    const int cbase = __builtin_amdgcn_readfirstlane(chalf << 5);  // wave-uniform -> s_load
    const int row0  = blockIdx.x * RPB;

    if (tid < CC) colsumA[tid] = 0.f;

    const int sr = tid >> 3;            // staging row 0..31 (+32p)
    const int sj = (tid & 7) * 4;       // staging j offset
    const float* xstage = x + (size_t)(row0 + sr) * DD + sj;

    float s[32];
#pragma unroll
    for (int cc = 0; cc < 32; ++cc) s[cc] = 0.f;

    // ---------------- phase 1: scores, software-pipelined staging ----------
    float4 rp[4];
#pragma unroll
    for (int p = 0; p < 4; ++p)
        rp[p] = *(const float4*)(xstage + (size_t)p * 32 * DD);
#pragma unroll
    for (int p = 0; p < 4; ++p) {
        float* dst = &bufA[XST * (sr + 32 * p) + sj];
        *(float2*)dst       = make_float2(rp[p].x, rp[p].y);
        *(float2*)(dst + 2) = make_float2(rp[p].z, rp[p].w);
    }
    __syncthreads();

    for (int ch = 0; ch < 4; ++ch) {
        const int j0 = ch * CHW;
        if (ch < 3) {   // issue next chunk's loads; latency hides under compute
#pragma unroll
            for (int p = 0; p < 4; ++p)
                rp[p] = *(const float4*)(xstage + (size_t)p * 32 * DD + (j0 + CHW));
        }
        const float* xrow = &bufA[XST * rloc];
        for (int js = 0; js < CHW; js += 4) {
            const float2 x01 = *(const float2*)(xrow + js);
            const float2 x23 = *(const float2*)(xrow + js + 2);
            const float* dcol = dict + (size_t)cbase * DD + (j0 + js);
#pragma unroll
            for (int cc = 0; cc < 32; ++cc) {
                const float* dp = dcol + cc * DD;   // uniform address -> s_load
                float acc = s[cc];
                acc = fmaf(x01.x, dp[0], acc);
                acc = fmaf(x01.y, dp[1], acc);
                acc = fmaf(x23.x, dp[2], acc);
                acc = fmaf(x23.y, dp[3], acc);
                s[cc] = acc;
            }
        }
        if (ch < 3) {
            __syncthreads();   // all consumers of bufA done
#pragma unroll
            for (int p = 0; p < 4; ++p) {
                float* dst = &bufA[XST * (sr + 32 * p) + sj];
                *(float2*)dst       = make_float2(rp[p].x, rp[p].y);
                *(float2*)(dst + 2) = make_float2(rp[p].z, rp[p].w);
            }
            __syncthreads();
        }
    }

    // ---------------- phase 2: max across the pair ----------------
    float lm = s[0];
#pragma unroll
    for (int cc = 1; cc < 32; ++cc) lm = fmaxf(lm, s[cc]);
    red2[rloc][chalf] = lm;
    __syncthreads();
    const float mg = fmaxf(red2[rloc][0], red2[rloc][1]);
    __syncthreads();

    // ---------------- top-4 local on RAW s (strict '>' => lowest index) ----
    float tv[4]; int ti[4];
    {
        float best = NEGF; int bi = 0;
#pragma unroll
        for (int cc = 0; cc < 32; ++cc) { if (s[cc] > best) { best = s[cc]; bi = cc; } }
        tv[0] = best; ti[0] = bi;
    }
    {
        float best = NEGF; int bi = 0;
#pragma unroll
        for (int cc = 0; cc < 32; ++cc) {
            const float v = (cc == ti[0]) ? NEGF : s[cc];
            if (v > best) { best = v; bi = cc; }
        }
        tv[1] = best; ti[1] = bi;
    }
    {
        float best = NEGF; int bi = 0;
#pragma unroll
        for (int cc = 0; cc < 32; ++cc) {
            const float v = (cc == ti[0] || cc == ti[1]) ? NEGF : s[cc];
            if (v > best) { best = v; bi = cc; }
        }
        tv[2] = best; ti[2] = bi;
    }
    {
        float best = NEGF; int bi = 0;
#pragma unroll
        for (int cc = 0; cc < 32; ++cc) {
            const float v = (cc == ti[0] || cc == ti[1] || cc == ti[2]) ? NEGF : s[cc];
            if (v > best) { best = v; bi = cc; }
        }
        tv[3] = best; ti[3] = bi;
    }

    // ---------------- single exp pass: s -> e, then normalize to q ---------
    float lz = 0.f;
#pragma unroll
    for (int cc = 0; cc < 32; ++cc) {
        const float e = __expf((s[cc] - mg) * INV_TEMP);
        s[cc] = e; lz += e;
    }
    red2[rloc][chalf] = lz;
    __syncthreads();
    const float rZ = 1.f / (red2[rloc][0] + red2[rloc][1]);
#pragma unroll
    for (int cc = 0; cc < 32; ++cc) s[cc] *= rZ;

    // ---------------- top-4 merge across the pair (via LDS) ---------------
    float* t4v = bufA;
    int*   t4i = (int*)(bufA + 1024);
    {
        const int b4 = (rloc * 2 + chalf) * 4;
#pragma unroll
        for (int k = 0; k < 4; ++k) { t4v[b4 + k] = tv[k]; t4i[b4 + k] = cbase + ti[k]; }
    }
    __syncthreads();
    float cv[8]; int ci[8];
#pragma unroll
    for (int h = 0; h < 2; ++h) {
#pragma unroll
        for (int k = 0; k < 4; ++k) {
            cv[h * 4 + k] = t4v[(rloc * 2 + h) * 4 + k];
            ci[h * 4 + k] = t4i[(rloc * 2 + h) * 4 + k];
        }
    }
    __syncthreads();   // bufA free for reuse after this

    // ranks over 8 candidates (total order: value desc, index asc on ties)
    int rank[8];
#pragma unroll
    for (int j = 0; j < 8; ++j) rank[j] = 0;
#pragma unroll
    for (int j = 0; j < 8; ++j) {
#pragma unroll
        for (int k = 0; k < 8; ++k) {
            if (k == j) continue;
            const bool kg = (cv[k] > cv[j]) || (cv[k] == cv[j] && ci[k] < ci[j]);
            rank[j] += kg ? 1 : 0;
        }
    }
    float sv[4]; int si[4];
#pragma unroll
    for (int t2 = 0; t2 < 4; ++t2) { sv[t2] = NEGF; si[t2] = 0; }
#pragma unroll
    for (int j = 0; j < 8; ++j) {
#pragma unroll
        for (int t2 = 0; t2 < 4; ++t2) {
            const bool sel = (rank[j] == t2);
            sv[t2] = sel ? cv[j] : sv[t2];
            si[t2] = sel ? ci[j] : si[t2];
        }
    }
    // softmax over the 4 selected scores (order-invariant for the combine)
    const float e1 = __expf((sv[1] - sv[0]) * INV_TEMP);
    const float e2 = __expf((sv[2] - sv[0]) * INV_TEMP);
    const float e3 = __expf((sv[3] - sv[0]) * INV_TEMP);
    const float rZ4 = 1.f / (1.f + e1 + e2 + e3);
    const float w0 = rZ4, w1 = e1 * rZ4, w2 = e2 * rZ4, w3 = e3 * rZ4;

    // publish per-row routing for the streaming epilogue (pair computes
    // identical values -> chalf==0 writes)
    if (chalf == 0) {
        *(float4*)&w4s[rloc][0] = make_float4(w0, w1, w2, w3);
        *(int4*)&si4s[rloc][0]  = make_int4(si[0], si[1], si[2], si[3]);
    }

    // ---------------- q -> LDS (bf16) -> coalesced global store -----------
    {
        unsigned* qs = (unsigned*)bufA;
        const int base = XST * rloc + 16 * chalf;
#pragma unroll
        for (int k2 = 0; k2 < 16; k2 += 2) {
            uint2 w;
            w.x = (f2bf(s[2 * k2 + 1]) << 16) | f2bf(s[2 * k2 + 0]);
            w.y = (f2bf(s[2 * k2 + 3]) << 16) | f2bf(s[2 * k2 + 2]);
            *(uint2*)&qs[base + k2] = w;
        }
        __syncthreads();
        unsigned* qdst = qg + (size_t)blockIdx.x * (RPB * 32);
#pragma unroll
        for (int k4 = 0; k4 < 4; ++k4) {
            const int gd  = k4 * 1024 + tid * 4;
            const int row = gd >> 5, kk = gd & 31;
            const uint2 a = *(const uint2*)&qs[XST * row + kk];
            const uint2 b = *(const uint2*)&qs[XST * row + kk + 2];
            uint4 o; o.x = a.x; o.y = a.y; o.z = b.x; o.w = b.y;
            *(uint4*)&qdst[gd] = o;
        }
        // column sums from staged bf16 q: lane -> column pair, 16 rows each.
        // Banks (2*(rr0+rr)+cp)%32 distinct across half-wave -> conflict-free.
        const int cp  = tid & 31;
        const int rr0 = (tid >> 5) * 16;
        float c0 = 0.f, c1 = 0.f;
#pragma unroll
        for (int rr = 0; rr < 16; ++rr) {
            const unsigned u = qs[XST * (rr0 + rr) + cp];
            c0 += bflo(u); c1 += bfhi(u);
        }
        atomicAdd(&colsumA[2 * cp + 0], c0);   // 8-way only
        atomicAdd(&colsumA[2 * cp + 1], c1);
    }
    __syncthreads();
    if (tid < CC) colpart[blockIdx.x * CC + tid] = colsumA[tid];

    // ---------------- phase 3: barrier-free streaming epilogue ------------
    // gd layout: fully coalesced x re-read (L3-hot), dict gathers contiguous
    // 512B per half-wave (L1-resident), coalesced xc/xr stores.
#pragma unroll 2
    for (int it = 0; it < 16; ++it) {
        const int gd  = it * 1024 + tid * 4;
        const int row = gd >> 7;
        const int dd  = gd & 127;
        const float4 wv = *(const float4*)&w4s[row][0];
        const int4  iv  = *(const int4*)&si4s[row][0];
        const size_t go = (size_t)(row0 + row) * DD + dd;
        const float4 xv = *(const float4*)(x + go);
        const float4 d0 = *(const float4*)(dict + (size_t)iv.x * DD + dd);
        const float4 d1 = *(const float4*)(dict + (size_t)iv.y * DD + dd);
        const float4 d2 = *(const float4*)(dict + (size_t)iv.z * DD + dd);
        const float4 d3 = *(const float4*)(dict + (size_t)iv.w * DD + dd);
        float4 c4, r4;
        c4.x = fmaf(wv.w, d3.x, fmaf(wv.z, d2.x, fmaf(wv.y, d1.x, wv.x * d0.x)));
        c4.y = fmaf(wv.w, d3.y, fmaf(wv.z, d2.y, fmaf(wv.y, d1.y, wv.x * d0.y)));
        c4.z = fmaf(wv.w, d3.z, fmaf(wv.z, d2.z, fmaf(wv.y, d1.z, wv.x * d0.z)));
        c4.w = fmaf(wv.w, d3.w, fmaf(wv.z, d2.w, fmaf(wv.y, d1.w, wv.x * d0.w)));
        r4.x = xv.x - c4.x; r4.y = xv.y - c4.y;
        r4.z = xv.z - c4.z; r4.w = xv.w - c4.w;
        *(float4*)(xcg + go) = c4;
        *(float4*)(xrg + go) = r4;
    }
}

// ---------------------------------------------------------------------------
// k_colsum: reduce colpart[1024][64] -> colsum[64]
// ---------------------------------------------------------------------------
__global__ void k_colsum(const float* __restrict__ colpart, float* __restrict__ colsum)
{
    const int tid = threadIdx.x;                     // grid 16 x 256
    const int c   = tid & 63;
    const int seg = blockIdx.x * 4 + (tid >> 6);     // 0..63
    float v = 0.f;
#pragma unroll
    for (int b = 0; b < 16; ++b)
        v += colpart[(seg * 16 + b) * 64 + c];
    atomicAdd(&colsum[c], v);
}

// ---------------------------------------------------------------------------
// k_kl: per-row KL from bf16 q (LDS-staged coalesced reads)
// log p - log q = log q - log F_c - log S_row
// ---------------------------------------------------------------------------
__global__ __launch_bounds__(256, 2) void k_kl(
    const unsigned* __restrict__ qg, const float* __restrict__ colsum,
    float* __restrict__ klacc)
{
    __shared__ __align__(8) unsigned qs[256 * XST];  // 34816 B
    __shared__ float rF[CC], lF[CC];
    __shared__ float kred[4];
    const int tid = threadIdx.x;
    if (tid < CC) { const float F = colsum[tid]; rF[tid] = 1.f / F; lF[tid] = __logf(F); }
    const unsigned* qb = qg + (size_t)blockIdx.x * 8192;
#pragma unroll
    for (int g = 0; g < 8; ++g) {
        const int gd = g * 1024 + tid * 4;
        const uint4 v = *(const uint4*)(qb + gd);
        const int row = gd >> 5, kk = gd & 31;
        *(uint2*)&qs[XST * row + kk]     = make_uint2(v.x, v.y);
        *(uint2*)&qs[XST * row + kk + 2] = make_uint2(v.z, v.w);
    }
    __syncthreads();
    const unsigned* qr = &qs[XST * tid];
    unsigned u[32];
#pragma unroll
    for (int k = 0; k < 32; k += 2) {
        const uint2 t2 = *(const uint2*)&qr[k];
        u[k] = t2.x; u[k + 1] = t2.y;
    }
    float S = 0.f;
#pragma unroll
    for (int k = 0; k < 32; ++k) {
        const float f0 = bflo(u[k]), f1 = bfhi(u[k]);
        S = fmaf(f0 * f0, rF[2 * k], S);
        S = fmaf(f1 * f1, rF[2 * k + 1], S);
    }
    const float rS = 1.f / S;
    const float lS = __logf(S);
    float acc = 0.f;
#pragma unroll
    for (int k = 0; k < 32; ++k) {
        const float f0 = bflo(u[k]), f1 = bfhi(u[k]);
        const float p0 = f0 * f0 * rF[2 * k] * rS;
        const float p1 = f1 * f1 * rF[2 * k + 1] * rS;
        acc += p0 * (__logf(f0) - lF[2 * k] - lS);
        acc += p1 * (__logf(f1) - lF[2 * k + 1] - lS);
    }
#pragma unroll
    for (int off = 32; off > 0; off >>= 1) acc += __shfl_down(acc, off, 64);
    if ((tid & 63) == 0) kred[tid >> 6] = acc;
    __syncthreads();
    if (tid == 0) atomicAdd(klacc, kred[0] + kred[1] + kred[2] + kred[3]);
}

// ---------------------------------------------------------------------------
// k_ortho: sum over (i,j) of (gram[i][j]-I)^2
// ---------------------------------------------------------------------------
__global__ __launch_bounds__(256) void k_ortho(
    const float* __restrict__ dict, float* __restrict__ oacc)
{
    __shared__ __align__(16) float dlds[CC * LDSS];
    const int tid = threadIdx.x;
    for (int idx = tid; idx < CC * DD; idx += 256)
        dlds[(idx >> 7) * LDSS + (idx & 127)] = dict[idx];
    __syncthreads();

    const int e = blockIdx.x * 256 + tid;   // grid 16 -> e in [0,4096)
    const int i = e >> 6, jj = e & 63;
    const float* di = &dlds[i * LDSS];
    const float* dj = &dlds[jj * LDSS];
    float g = 0.f;
#pragma unroll 8
    for (int d = 0; d < DD; d += 4) {
        const float4 a = *(const float4*)(di + d);
        const float4 b = *(const float4*)(dj + d);
        g += a.x * b.x + a.y * b.y + a.z * b.z + a.w * b.w;
    }
    const float diff = g - ((i == jj) ? 1.f : 0.f);
    float v = diff * diff;
#pragma unroll
    for (int off = 32; off > 0; off >>= 1)
        v += __shfl_down(v, off, 64);
    if ((tid & 63) == 0) atomicAdd(oacc, v);
}

// ---------------------------------------------------------------------------
__global__ void k_final(const float* __restrict__ klacc,
                        const float* __restrict__ oacc,
                        float* __restrict__ out_scalar)
{
    out_scalar[0] = 0.5f * (klacc[0] / (float)ROWS) + 0.1f * (oacc[0] / 4096.f);
}

// ---------------------------------------------------------------------------
extern "C" void kernel_launch(void* const* d_in, const int* in_sizes, int n_in,
                              void* d_out, int out_size, void* d_ws, size_t ws_size,
                              hipStream_t stream)
{
    const float* x    = (const float*)d_in[0];   // (16, 8192, 128)
    const float* dict = (const float*)d_in[1];   // (64, 128)
    float* out = (float*)d_out;
    float* xcg = out;                               // (B,N,D)
    float* xrg = out + (size_t)ROWS * DD;           // (B,N,D)
    float* aux = out + 2 * (size_t)ROWS * DD;       // scalar

    float* ws      = (float*)d_ws;
    float* colsum  = ws;                 // 64 floats
    float* klacc   = ws + 64;            // 1
    float* oacc    = ws + 65;            // 1
    float* colpart = ws + 256;           // 1024*64 floats = 256 KB
    unsigned* qbuf = (unsigned*)(ws + 256 + 1024 * 64);  // 131072*32 dwords = 16.75 MB

    hipMemsetAsync(d_ws, 0, 1024, stream);

    k_main  <<<ROWS / RPB, 256, 0, stream>>>(x, dict, xcg, xrg, qbuf, colpart);
    k_colsum<<<16,         256, 0, stream>>>(colpart, colsum);
    k_kl    <<<ROWS / 256, 256, 0, stream>>>(qbuf, colsum, klacc);
    k_ortho <<<16,         256, 0, stream>>>(dict, oacc);
    k_final <<<1,          1,   0, stream>>>(klacc, oacc, aux);
}